// Round 5
// baseline (1764.683 us; speedup 1.0000x reference)
//
#include <hip/hip_runtime.h>
#include <math.h>

// Problem: B=256, TQ=64, N=196, E=1024, K=512. ~188 GF logical.
// G1/G2/G3/G4 on bf16 MFMA with PRE-SPLIT hi/lo operands (error ~2^-17):
// split/transpose paid once in memory-bound passes, GEMM stages via
// global_load_lds (no VALU split, no LDS bank conflicts). G5a/G6a/tails fp32.

typedef float f32x4 __attribute__((ext_vector_type(4)));
typedef short bf16x8 __attribute__((ext_vector_type(8)));
typedef unsigned short u16;

__device__ __forceinline__ float fast_tanh(float x) {
    float ax = fabsf(x);
    float e  = __expf(-2.0f * ax);
    float r  = (1.0f - e) / (1.0f + e);
    return copysignf(r, x);
}
__device__ __forceinline__ u16 f2bf(float f) {
    unsigned u = __float_as_uint(f);
    u += 0x7FFF + ((u >> 16) & 1);          // RNE
    return (u16)(u >> 16);
}
__device__ __forceinline__ void split_hl(float f, u16 &h, u16 &l) {
    h = f2bf(f);
    float fh = __uint_as_float((unsigned)h << 16);
    l = f2bf(f - fh);
}
__device__ __forceinline__ void gload_lds16(const u16* g, u16* l) {
    __builtin_amdgcn_global_load_lds(
        (const __attribute__((address_space(1))) unsigned int*)(const void*)g,
        (__attribute__((address_space(3))) unsigned int*)(void*)l, 16, 0, 0);
}

// ---------------------------------------------------------------------------
// P0: transpose + split. in [R, C] fp32 (row stride C) -> out [C, R] bf16 hi/lo.
// Batched via blockIdx.z with strides inB/outB (elements). R % 64 == 0.
// ---------------------------------------------------------------------------
__global__ __launch_bounds__(256) void transpose_split_kernel(
    const float* __restrict__ in, u16* __restrict__ oh, u16* __restrict__ ol,
    const int R, const int C, const long inB, const long outB)
{
    __shared__ float tile[64][65];
    const int t = threadIdx.x;
    const int c0 = blockIdx.x * 64;
    const int r0 = blockIdx.y * 64;
    const long bz = blockIdx.z;
    const float* ib = in + bz * inB;

    #pragma unroll
    for (int i = 0; i < 16; ++i) {
        int idx = i * 256 + t;
        int rl = idx >> 6, cl = idx & 63;
        float v = 0.f;
        if (c0 + cl < C) v = ib[(size_t)(r0 + rl) * C + c0 + cl];
        tile[rl][cl] = v;
    }
    __syncthreads();
    #pragma unroll
    for (int i = 0; i < 16; ++i) {
        int idx = i * 256 + t;
        int cl = idx >> 6, rl = idx & 63;     // out row = c, out col = r (contig)
        if (c0 + cl < C) {
            float v = tile[rl][cl];
            u16 h, l;
            split_hl(v, h, l);
            size_t o = bz * outB + (size_t)(c0 + cl) * R + r0 + rl;
            oh[o] = h; ol[o] = l;
        }
    }
}

// P2: flat split fp32 -> bf16 hi/lo. n4 = element_count/4.
__global__ __launch_bounds__(256) void split_flat_kernel(
    const float* __restrict__ in, u16* __restrict__ oh, u16* __restrict__ ol,
    const int n4)
{
    for (int i = blockIdx.x * 256 + threadIdx.x; i < n4; i += gridDim.x * 256) {
        float4 v = ((const float4*)in)[i];
        u16 h0,h1,h2,h3, l0,l1,l2,l3;
        split_hl(v.x,h0,l0); split_hl(v.y,h1,l1);
        split_hl(v.z,h2,l2); split_hl(v.w,h3,l3);
        ((ushort4*)oh)[i] = make_ushort4(h0,h1,h2,h3);
        ((ushort4*)ol)[i] = make_ushort4(l0,l1,l2,l3);
    }
}

// ---------------------------------------------------------------------------
// bf16 NT GEMM: C[m,n] = ACT( sum_k A[m,k]*B[n,k] + bias[n] ), A/B pre-split
// hi/lo bf16, k-contiguous rows. 3 MFMAs per product (hh+hl+lh).
// Waves: WM x WN grid of 64x64 per-wave tiles. Block = WM*WN*64 threads.
// Staging: global_load_lds(16B) into panel layout: panel = 16 rows x 32 k,
//   lane slot l <-> (row l&15, k-chunk l>>4), 1024B/panel -> conflict-free
//   b128 reads and linear writes. Rows clamped to [0,M-1]/[0,N-1] (epilogue
//   guards discard). K % 32 == 0.
// OUTMODE: 0 = f32(+bias), 1 = f32 tanh, 2 = bf16 hi/lo pair(+bias).
// ---------------------------------------------------------------------------
template<int WM, int WN, int OUTMODE, bool BATCHED>
__global__ __launch_bounds__(WM*WN*64) void bf_gemm(
    const u16* __restrict__ Ah, const u16* __restrict__ Al,
    const u16* __restrict__ Bh, const u16* __restrict__ Bl,
    const float* __restrict__ bias,
    float* __restrict__ Cf, u16* __restrict__ Ch, u16* __restrict__ Cl,
    const int M, const int N, const int K,
    const int aB, const int bB, const long cB, const int ldc)
{
    constexpr int NW = WM * WN;
    constexpr int AP = WM * 4;          // A panels per K-step
    constexpr int BP = WN * 4;
    constexpr int TOT = (AP + BP) * 2;  // jobs incl. hi/lo planes
    __shared__ __align__(16) u16 smem[(AP + BP) * 2 * 512];

    const int t  = threadIdx.x;
    const int wid = t >> 6, l = t & 63;
    const int wm = wid / WN, wn = wid % WN;
    const int n0 = blockIdx.x * (WN * 64);
    const int m0 = blockIdx.y * (WM * 64);
    const int bz = BATCHED ? blockIdx.z : 0;

    f32x4 acc[4][4];
    #pragma unroll
    for (int p = 0; p < 4; ++p)
        #pragma unroll
        for (int q = 0; q < 4; ++q)
            acc[p][q] = (f32x4){0.f, 0.f, 0.f, 0.f};

    const int lk = (l >> 4) << 3;       // per-lane k offset within 32
    const int lr = l & 15;              // per-lane row within panel

    for (int k0 = 0; k0 < K; k0 += 32) {
        #pragma unroll
        for (int j = wid; j < TOT; j += NW) {
            if (j < 2 * AP) {
                int plane = j / AP, p = j % AP;
                int gm = m0 + p * 16 + lr; gm = min(gm, M - 1);
                const u16* src = plane ? Al : Ah;
                const u16* g = src + (BATCHED ? (size_t)bz * aB : 0)
                             + (size_t)gm * K + k0 + lk;
                gload_lds16(g, smem + (plane * AP + p) * 512);
            } else {
                int jj = j - 2 * AP;
                int plane = jj / BP, p = jj % BP;
                int gn = n0 + p * 16 + lr; gn = min(gn, N - 1);
                const u16* src = plane ? Bl : Bh;
                const u16* g = src + (BATCHED ? (size_t)bz * bB : 0)
                             + (size_t)gn * K + k0 + lk;
                gload_lds16(g, smem + (2 * AP + plane * BP + p) * 512);
            }
        }
        __syncthreads();                // drains vmcnt -> LDS ready

        bf16x8 a_h[4], a_l[4], b_h[4], b_l[4];
        #pragma unroll
        for (int p = 0; p < 4; ++p) {
            const u16* pa = smem + (wm * 4 + p) * 512 + l * 8;
            a_h[p] = *(const bf16x8*)pa;
            a_l[p] = *(const bf16x8*)(pa + AP * 512);
        }
        #pragma unroll
        for (int q = 0; q < 4; ++q) {
            const u16* pb = smem + (2 * AP + wn * 4 + q) * 512 + l * 8;
            b_h[q] = *(const bf16x8*)pb;
            b_l[q] = *(const bf16x8*)(pb + BP * 512);
        }
        #pragma unroll
        for (int p = 0; p < 4; ++p)
            #pragma unroll
            for (int q = 0; q < 4; ++q)
                acc[p][q] = __builtin_amdgcn_mfma_f32_16x16x32_bf16(a_h[p], b_h[q], acc[p][q], 0, 0, 0);
        #pragma unroll
        for (int p = 0; p < 4; ++p)
            #pragma unroll
            for (int q = 0; q < 4; ++q)
                acc[p][q] = __builtin_amdgcn_mfma_f32_16x16x32_bf16(a_h[p], b_l[q], acc[p][q], 0, 0, 0);
        #pragma unroll
        for (int p = 0; p < 4; ++p)
            #pragma unroll
            for (int q = 0; q < 4; ++q)
                acc[p][q] = __builtin_amdgcn_mfma_f32_16x16x32_bf16(a_l[p], b_h[q], acc[p][q], 0, 0, 0);
        __syncthreads();
    }

    // Epilogue. C/D HW map (m89): col = lane&15, row = (lane>>4)*4 + reg.
    const int colp = l & 15;
    const int rquad = (l >> 4) * 4;
    #pragma unroll
    for (int q = 0; q < 4; ++q) {
        int col = n0 + wn * 64 + q * 16 + colp;
        if (col >= N) continue;
        float bv = bias ? bias[col] : 0.f;
        #pragma unroll
        for (int p = 0; p < 4; ++p) {
            #pragma unroll
            for (int i = 0; i < 4; ++i) {
                int row = m0 + wm * 64 + p * 16 + rquad + i;
                if (row >= M) continue;
                float v = acc[p][q][i] + bv;
                size_t ci = (BATCHED ? (size_t)bz * cB : 0) + (size_t)row * ldc + col;
                if (OUTMODE == 0) {
                    Cf[ci] = v;
                } else if (OUTMODE == 1) {
                    Cf[ci] = fast_tanh(v);
                } else {
                    u16 h, lo2;
                    split_hl(v, h, lo2);
                    Ch[ci] = h; Cl[ci] = lo2;
                }
            }
        }
    }
}

// ---------------------------------------------------------------------------
// fp32 vector GEMM (G5a / G6a)
// ---------------------------------------------------------------------------
template<int BM,int BN,int BK,int TM,int TN,int ALOAD,int BLOAD,int NBF,int ACT,bool BATCHED>
__global__ __launch_bounds__(256) void gemm_k(
    const float* __restrict__ A, const float* __restrict__ Bm,
    const float* __restrict__ bias, const float* __restrict__ Dadd,
    float* __restrict__ C,
    const int M, const int Nn, const int K,
    const int ab, const int am, const int ak,
    const int bb, const int bk, const int bn,
    const int cb, const int cm)
{
    static_assert(BK == 16, "staging math assumes BK==16");
    __shared__ __align__(16) float As[BK][BM + 4];
    __shared__ __align__(16) float Bs[BK][BN + 4];

    const int t  = threadIdx.x;
    const int n0 = blockIdx.x * BN;
    const int m0 = blockIdx.y * BM;
    const int bz = BATCHED ? blockIdx.z : 0;
    const int w  = t >> 6;
    const int l  = t & 63;
    const int tx = l & 7, ty = l >> 3;
    const int mloc = (w >> 1) * (BM / 2) + ty * TM;
    const int nloc = (w & 1)  * (BN / 2) + tx * TN;

    float acc[TM][TN];
    #pragma unroll
    for (int i = 0; i < TM; ++i)
        #pragma unroll
        for (int j = 0; j < TN; ++j) acc[i][j] = 0.f;

    for (int k0 = 0; k0 < K; k0 += BK) {
        if (ALOAD == 0) {
            constexpr int NF4 = (BM * BK) / (4 * 256);
            #pragma unroll
            for (int i = 0; i < NF4; ++i) {
                int f4i = i * 256 + t;
                int row = f4i >> 2;
                int kq  = (f4i & 3) << 2;
                int gm = m0 + row, gk = k0 + kq;
                float4 v = make_float4(0.f, 0.f, 0.f, 0.f);
                if (gm < M) {
                    int br, r;
                    if (BATCHED)      { br = bz; r = gm; }
                    else if (NBF > 0) { br = gm / NBF; r = gm - br * NBF; }
                    else              { br = 0;  r = gm; }
                    const float* p = A + (size_t)br * ab + (size_t)r * am + gk;
                    if (gk + 4 <= K) v = *(const float4*)p;
                    else {
                        float tv[4] = {0.f, 0.f, 0.f, 0.f};
                        #pragma unroll
                        for (int j = 0; j < 4; ++j) if (gk + j < K) tv[j] = p[j];
                        v = make_float4(tv[0], tv[1], tv[2], tv[3]);
                    }
                }
                As[kq + 0][row] = v.x; As[kq + 1][row] = v.y;
                As[kq + 2][row] = v.z; As[kq + 3][row] = v.w;
            }
        } else {
            constexpr int NF4 = (BM * BK) / (4 * 256);
            #pragma unroll
            for (int i = 0; i < NF4; ++i) {
                int f4i = i * 256 + t;
                int m4 = f4i % (BM / 4);
                int kk = f4i / (BM / 4);
                int gm = m0 + m4 * 4, gk = k0 + kk;
                float4 v = make_float4(0.f, 0.f, 0.f, 0.f);
                if (gm < M && gk < K) {
                    int br, r;
                    if (BATCHED)      { br = bz; r = gm; }
                    else if (NBF > 0) { br = gm / NBF; r = gm - br * NBF; }
                    else              { br = 0;  r = gm; }
                    const float* p = A + (size_t)br * ab + (size_t)r + (size_t)gk * ak;
                    v = *(const float4*)p;
                }
                *(float4*)&As[kk][m4 * 4] = v;
            }
        }
        if (BLOAD == 0) {
            constexpr int NF4 = (BK * BN) / (4 * 256);
            #pragma unroll
            for (int i = 0; i < NF4; ++i) {
                int f4i = i * 256 + t;
                int nq2 = f4i % (BN / 4);
                int kk = f4i / (BN / 4);
                int gn = n0 + nq2 * 4, gk = k0 + kk;
                float4 v = make_float4(0.f, 0.f, 0.f, 0.f);
                if (gk < K && gn + 4 <= Nn) {
                    const float* p = Bm + (size_t)bz * bb + (size_t)gk * bk + gn;
                    v = *(const float4*)p;
                }
                *(float4*)&Bs[kk][nq2 * 4] = v;
            }
        } else {
            constexpr int NF4 = (BK * BN) / (4 * 256);
            #pragma unroll
            for (int i = 0; i < NF4; ++i) {
                int f4i = i * 256 + t;
                int col = f4i >> 2;
                int kq  = (f4i & 3) << 2;
                int gn = n0 + col, gk = k0 + kq;
                float4 v = make_float4(0.f, 0.f, 0.f, 0.f);
                if (gn < Nn) {
                    const float* p = Bm + (size_t)bz * bb + (size_t)gn * bn + gk;
                    if (gk + 4 <= K) v = *(const float4*)p;
                    else {
                        float tv[4] = {0.f, 0.f, 0.f, 0.f};
                        #pragma unroll
                        for (int j = 0; j < 4; ++j) if (gk + j < K) tv[j] = p[j];
                        v = make_float4(tv[0], tv[1], tv[2], tv[3]);
                    }
                }
                Bs[kq + 0][col] = v.x; Bs[kq + 1][col] = v.y;
                Bs[kq + 2][col] = v.z; Bs[kq + 3][col] = v.w;
            }
        }
        __syncthreads();
        #pragma unroll
        for (int kk = 0; kk < BK; ++kk) {
            float a[TM], b[TN];
            #pragma unroll
            for (int i = 0; i < TM; i += 4)
                *(float4*)&a[i] = *(const float4*)&As[kk][mloc + i];
            #pragma unroll
            for (int j = 0; j < TN; j += 4)
                *(float4*)&b[j] = *(const float4*)&Bs[kk][nloc + j];
            #pragma unroll
            for (int i = 0; i < TM; ++i)
                #pragma unroll
                for (int j = 0; j < TN; ++j)
                    acc[i][j] = fmaf(a[i], b[j], acc[i][j]);
        }
        __syncthreads();
    }
    #pragma unroll
    for (int i = 0; i < TM; ++i) {
        int gm = m0 + mloc + i;
        if (gm >= M) continue;
        int br, r;
        if (BATCHED)      { br = bz; r = gm; }
        else if (NBF > 0) { br = gm / NBF; r = gm - br * NBF; }
        else              { br = 0;  r = gm; }
        const size_t crow = (size_t)br * cb + (size_t)r * cm;
        #pragma unroll
        for (int j = 0; j < TN; ++j) {
            int gn = n0 + nloc + j;
            if (gn >= Nn) continue;
            float v = acc[i][j];
            if (bias) v += bias[gn];
            size_t ci = crow + gn;
            if (Dadd) v += Dadd[ci];
            if (ACT == 1) v = fast_tanh(v);
            C[ci] = v;
        }
    }
}

// img branch tail
__global__ __launch_bounds__(256) void img_branch_kernel(
    const float* __restrict__ ih,
    const float* __restrict__ wia, const float* __restrict__ bia,
    const float* __restrict__ img_feat,
    float* __restrict__ out)
{
    const int b = blockIdx.x;
    const int t = threadIdx.x;
    const int w = t >> 6, l = t & 63;
    __shared__ float s_w[512];
    __shared__ __align__(16) float sc[200];
    __shared__ float red[8];

    for (int i = t; i < 512; i += 256) s_w[i] = wia[i];
    __syncthreads();

    const float* ihb = ih + (size_t)b * 196 * 512;
    for (int n = w; n < 196; n += 4) {
        const float* row = ihb + n * 512;
        float p = 0.f;
        for (int k = l; k < 512; k += 64) p = fmaf(s_w[k], row[k], p);
        #pragma unroll
        for (int off = 32; off > 0; off >>= 1) p += __shfl_xor(p, off);
        if (l == 0) sc[n] = p + bia[0];
    }
    __syncthreads();

    float v = (t < 196) ? sc[t] : -3.402823466e38f;
    float m = v;
    #pragma unroll
    for (int off = 32; off > 0; off >>= 1) m = fmaxf(m, __shfl_xor(m, off));
    if (l == 0) red[w] = m;
    __syncthreads();
    if (t == 0) {
        float mm = red[0];
        for (int i = 1; i < 4; ++i) mm = fmaxf(mm, red[i]);
        red[4] = mm;
    }
    __syncthreads();
    float mx = red[4];
    float e = (t < 196) ? __expf(v - mx) : 0.f;
    float s = e;
    #pragma unroll
    for (int off = 32; off > 0; off >>= 1) s += __shfl_xor(s, off);
    if (l == 0) red[w] = s;
    __syncthreads();
    if (t == 0) red[5] = 1.f / (red[0] + red[1] + red[2] + red[3]);
    __syncthreads();
    if (t < 196) sc[t] = e * red[5];
    __syncthreads();

    const float* ifb = img_feat + (size_t)b * 1024 * 196;
    for (int e0 = t; e0 < 1024; e0 += 256) {
        const float4* row = (const float4*)(ifb + (size_t)e0 * 196);
        float acc = 0.f;
        #pragma unroll 7
        for (int n4 = 0; n4 < 49; ++n4) {
            float4 x = row[n4];
            float4 a = *(const float4*)&sc[n4 * 4];
            acc = fmaf(x.x, a.x, acc);
            acc = fmaf(x.y, a.y, acc);
            acc = fmaf(x.z, a.z, acc);
            acc = fmaf(x.w, a.w, acc);
        }
        out[(size_t)b * 1024 + e0] = acc;
    }
}

// ques branch tail
__global__ __launch_bounds__(256) void ques_branch_kernel(
    const float* __restrict__ qh,
    const float* __restrict__ wqa, const float* __restrict__ bqa,
    const float* __restrict__ mask,
    const float* __restrict__ qf,
    float* __restrict__ out)
{
    const int b = blockIdx.x;
    const int t = threadIdx.x;
    const int w = t >> 6, l = t & 63;
    __shared__ float s_w[512];
    __shared__ float sq[64];

    for (int i = t; i < 512; i += 256) s_w[i] = wqa[i];
    __syncthreads();

    const float* qhb = qh + (size_t)b * 64 * 512;
    for (int q = w; q < 64; q += 4) {
        const float* row = qhb + q * 512;
        float p = 0.f;
        for (int k = l; k < 512; k += 64) p = fmaf(s_w[k], row[k], p);
        #pragma unroll
        for (int off = 32; off > 0; off >>= 1) p += __shfl_xor(p, off);
        if (l == 0) sq[q] = (p + bqa[0]) * mask[b * 64 + q];
    }
    __syncthreads();

    if (w == 0) {
        float v = sq[l];
        float m = v;
        #pragma unroll
        for (int off = 32; off > 0; off >>= 1) m = fmaxf(m, __shfl_xor(m, off));
        float e = __expf(v - m);
        float s = e;
        #pragma unroll
        for (int off = 32; off > 0; off >>= 1) s += __shfl_xor(s, off);
        sq[l] = e / s;
    }
    __syncthreads();

    const float* qfb = qf + (size_t)b * 64 * 1024;
    float4 acc = make_float4(0.f, 0.f, 0.f, 0.f);
    for (int q = 0; q < 64; ++q) {
        float a = sq[q];
        float4 x = *(const float4*)(qfb + q * 1024 + t * 4);
        acc.x = fmaf(a, x.x, acc.x);
        acc.y = fmaf(a, x.y, acc.y);
        acc.z = fmaf(a, x.z, acc.z);
        acc.w = fmaf(a, x.w, acc.w);
    }
    *(float4*)(out + (size_t)b * 1024 + t * 4) = acc;
}

extern "C" void kernel_launch(void* const* d_in, const int* in_sizes, int n_in,
                              void* d_out, int out_size, void* d_ws, size_t ws_size,
                              hipStream_t stream) {
    const float* qf  = (const float*)d_in[0];   // [256,64,1024]
    const float* imf = (const float*)d_in[1];   // [256,1024,196]
    const float* msk = (const float*)d_in[2];
    const float* Wc  = (const float*)d_in[3];   // [1024,1024]
    const float* bc  = (const float*)d_in[4];
    const float* Wq  = (const float*)d_in[5];   // [1024,512]
    const float* bq  = (const float*)d_in[6];
    const float* Wi  = (const float*)d_in[7];   // [1024,512]
    const float* bi  = (const float*)d_in[8];
    const float* wqa = (const float*)d_in[9];
    const float* bqa = (const float*)d_in[10];
    const float* wia = (const float*)d_in[11];
    const float* bia = (const float*)d_in[12];
    float* out = (float*)d_out;

    auto cdiv = [](int a, int b) { return (a + b - 1) / b; };

    // ---- workspace carve (bytes, 256-aligned) ----
    const size_t perBatch = 802816ull /*At hi+lo*/ + 262144ull /*qf hi+lo*/
                          + 802816ull /*ic hi+lo*/ + 131072ull /*qe*/
                          + 401408ull /*ie*/ + 50176ull /*wt*/ + 131072ull /*qh*/;
    const size_t fixedB = 8ull * 1024 * 1024 + 65536;   // weight splits + slack
    int CB = 256;
    while (CB > 1 && fixedB + (size_t)CB * perBatch > ws_size) CB >>= 1;

    char* cur = (char*)d_ws;
    auto carve = [&](size_t bytes) {
        char* p = cur;
        cur += (bytes + 255) & ~255ull;
        return p;
    };
    u16* WcT_h = (u16*)carve(1024ull*1024*2);
    u16* WcT_l = (u16*)carve(1024ull*1024*2);
    u16* WqT_h = (u16*)carve(512ull*1024*2);
    u16* WqT_l = (u16*)carve(512ull*1024*2);
    u16* WiT_h = (u16*)carve(512ull*1024*2);
    u16* WiT_l = (u16*)carve(512ull*1024*2);
    u16* At_h  = (u16*)carve((size_t)CB*196*1024*2);
    u16* At_l  = (u16*)carve((size_t)CB*196*1024*2);
    u16* qf_h  = (u16*)carve((size_t)CB*64*1024*2);
    u16* qf_l  = (u16*)carve((size_t)CB*64*1024*2);
    u16* ic_h  = (u16*)carve((size_t)CB*196*1024*2);
    u16* ic_l  = (u16*)carve((size_t)CB*196*1024*2);
    float* qe  = (float*)carve((size_t)CB*64*512*4);
    float* ie  = (float*)carve((size_t)CB*196*512*4);
    float* wt  = (float*)carve((size_t)CB*64*196*4);
    float* qh  = (float*)carve((size_t)CB*64*512*4);
    float* img_h = (float*)ic_h;   // reuse after G4 (CB*196*512*4 == ic_h bytes)

    dim3 blk(256);

    // ---- weight transpose+split (once per call) ----
    hipLaunchKernelGGL(transpose_split_kernel, dim3(16,16,1), blk, 0, stream,
        Wc, WcT_h, WcT_l, 1024, 1024, 0, 0);
    hipLaunchKernelGGL(transpose_split_kernel, dim3(8,16,1), blk, 0, stream,
        Wq, WqT_h, WqT_l, 1024, 512, 0, 0);
    hipLaunchKernelGGL(transpose_split_kernel, dim3(8,16,1), blk, 0, stream,
        Wi, WiT_h, WiT_l, 1024, 512, 0, 0);

    for (int c0 = 0; c0 < 256; c0 += CB) {
        const float* qfc  = qf  + (size_t)c0 * 65536;
        const float* imfc = imf + (size_t)c0 * 200704;
        const float* mskc = msk + (size_t)c0 * 64;
        float* outq = out + (size_t)c0 * 1024;
        float* outi = out + 262144 + (size_t)c0 * 1024;

        // P0: img transpose+split -> At [CB*196, 1024] hi/lo
        hipLaunchKernelGGL(transpose_split_kernel, dim3(4,16,CB), blk, 0, stream,
            imfc, At_h, At_l, 1024, 196, 200704, 200704);
        // P2: qf split -> [CB*64, 1024] hi/lo
        {
            int n4 = CB * 16384;
            hipLaunchKernelGGL(split_flat_kernel, dim3(min(2048, cdiv(n4,256))), blk, 0, stream,
                qfc, qf_h, qf_l, n4);
        }

        // G1: qe = qf @ Wq + bq        (M=CB*64, N=512, K=1024)
        hipLaunchKernelGGL((bf_gemm<2,2,0,false>), dim3(4, cdiv(CB*64,128), 1), blk, 0, stream,
            qf_h, qf_l, WqT_h, WqT_l, bq, qe, (u16*)nullptr, (u16*)nullptr,
            CB*64, 512, 1024, 0, 0, 0, 512);

        // G2: ic = At @ Wc + bc -> bf16 hi/lo   (M=CB*196, N=1024, K=1024)
        hipLaunchKernelGGL((bf_gemm<2,2,2,false>), dim3(8, cdiv(CB*196,128), 1), blk, 0, stream,
            At_h, At_l, WcT_h, WcT_l, bc, (float*)nullptr, ic_h, ic_l,
            CB*196, 1024, 1024, 0, 0, 0, 1024);

        // G3: ie = At @ Wi + bi        (M=CB*196, N=512, K=1024)
        hipLaunchKernelGGL((bf_gemm<2,2,0,false>), dim3(4, cdiv(CB*196,128), 1), blk, 0, stream,
            At_h, At_l, WiT_h, WiT_l, bi, ie, (u16*)nullptr, (u16*)nullptr,
            CB*196, 512, 1024, 0, 0, 0, 512);

        // G4: wt[b,q,n] = tanh( qf_b @ ic_b^T )  batched: M=64, N=196, K=1024
        hipLaunchKernelGGL((bf_gemm<1,2,1,true>), dim3(2, 1, CB), dim3(128), 0, stream,
            qf_h, qf_l, ic_h, ic_l, (const float*)nullptr, wt, (u16*)nullptr, (u16*)nullptr,
            64, 196, 1024, 65536, 200704, 12544, 196);

        // G5a: img_h = tanh(wt^T @ qe + ie)   (fp32, writes over ic region)
        hipLaunchKernelGGL((gemm_k<128,128,16,8,8,1,0,0,1,true>),
            dim3(4, 2, CB), blk, 0, stream,
            wt, qe, (const float*)nullptr, ie, img_h,
            196, 512, 64,  12544,1,196,  32768,512,1,  100352,512);

        // G5b: img tail
        hipLaunchKernelGGL(img_branch_kernel, dim3(CB), blk, 0, stream,
            img_h, wia, bia, imfc, outi);

        // G6a: qh = tanh(wt @ ie + qe)  (fp32)
        hipLaunchKernelGGL((gemm_k<64,64,16,4,4,0,0,0,1,true>),
            dim3(8, 1, CB), blk, 0, stream,
            wt, ie, (const float*)nullptr, qe, qh,
            64, 512, 196,  12544,196,1,  100352,512,1,  32768,512);

        // G6b: ques tail
        hipLaunchKernelGGL(ques_branch_kernel, dim3(CB), blk, 0, stream,
            qh, wqa, bqa, mskc, qfc, outq);
    }
}